// Round 1
// baseline (645.061 us; speedup 1.0000x reference)
//
#include <hip/hip_runtime.h>
#include <hip/hip_bf16.h>
#include <stdint.h>

// Qwen3 MLP with QDQ fake-quant, MI355X gfx950.
// M=8192 (B*S), H=1024, I=3072.
// Pipeline: memset scalars -> absmax(x) -> dequant weights (LPBQ fp32-exact -> bf16)
//   -> qdq(x)->bf16 -> GEMM1 (up&gate, bf16 MFMA, amax atomics) -> swiglu (h, amax)
//   -> o = qdq(h)*qdq(up) (amax) -> qdq(o) -> GEMM2 -> fp32 out.
// Workspace: ~136.3 MB bf16 intermediates.

#define M_ROWS 8192
#define H_DIM 1024
#define I_DIM 3072

typedef unsigned short u16;
typedef unsigned int u32;
typedef __attribute__((ext_vector_type(8))) short bf16x8;
typedef __attribute__((ext_vector_type(4))) float f32x4;

__device__ __forceinline__ float bf2f(u16 v) { return __uint_as_float(((u32)v) << 16); }
__device__ __forceinline__ u16 f2bf(float f) {
  u32 u = __float_as_uint(f);
  u32 r = (u + 0x7fffu + ((u >> 16) & 1u)) >> 16;
  return (u16)r;
}
// 16-bit symmetric fake quant-dequant (matches act_qdq: rint = round-half-even)
__device__ __forceinline__ float qdq16(float x, float s) {
  float q = rintf(x / s);
  q = fminf(fmaxf(q, -32768.f), 32767.f);
  return q * s;
}
__device__ __forceinline__ float scale_from(u32 bits) {
  return fmaxf(__uint_as_float(bits) / 32767.f, 1e-12f);
}

__device__ __forceinline__ void load_lds16(const u16* g, u16* lds) {
  __builtin_amdgcn_global_load_lds(
      (const __attribute__((address_space(1))) u32*)g,
      (__attribute__((address_space(3))) u32*)lds, 16, 0, 0);
}

// block = 256 threads (4 waves). Wave shuffle-max then LDS then one atomicMax.
__device__ __forceinline__ void block_amax_atomic(float mx, u32* slot) {
#pragma unroll
  for (int off = 32; off; off >>= 1) mx = fmaxf(mx, __shfl_xor(mx, off));
  __shared__ float red[4];
  const int lane = threadIdx.x & 63, wave = threadIdx.x >> 6;
  if (lane == 0) red[wave] = mx;
  __syncthreads();
  if (threadIdx.x == 0) {
    float m = fmaxf(fmaxf(red[0], red[1]), fmaxf(red[2], red[3]));
    atomicMax(slot, __float_as_uint(m));
  }
}

// ---------------- GEMM core (m97 structure) ----------------
// C[m,n] = sum_k A[m,k]*B[n,k]; A,B row-major with row stride K (bf16 bits).
// 128x128 tile, BK=32, 4 waves each computing 64x64 via 4x4 MFMA 16x16x32.
// Staging: global_load_lds width 16; LDS chunk position q holds global chunk
// q^(row&3) (XOR swizzle to spread banks); readers un-swizzle.
template <int K>
__device__ __forceinline__ void gemm_core(const u16* __restrict__ Ablk,
                                          const u16* __restrict__ Bblk,
                                          f32x4 acc[4][4]) {
  __shared__ __align__(16) u16 As[128 * 32];
  __shared__ __align__(16) u16 Bs[128 * 32];
  const int tid = threadIdx.x;
  const int lane = tid & 63, wave = tid >> 6;
  const int wm = wave >> 1, wn = wave & 1;
  const int quad = lane >> 4, mrow = lane & 15;

  // staging: 512 16B-chunks per tile; thread handles chunks tid and tid+256
  const int c0 = tid, c1 = tid + 256;
  const int r0 = c0 >> 2, g0 = ((c0 & 3) ^ (r0 & 3)) * 8;
  const int r1 = c1 >> 2, g1 = ((c1 & 3) ^ (r1 & 3)) * 8;
  const u16* a0 = Ablk + (size_t)r0 * K + g0;
  const u16* a1 = Ablk + (size_t)r1 * K + g1;
  const u16* b0 = Bblk + (size_t)r0 * K + g0;
  const u16* b1 = Bblk + (size_t)r1 * K + g1;
  u16* lA0 = &As[c0 * 8];
  u16* lA1 = &As[c1 * 8];
  u16* lB0 = &Bs[c0 * 8];
  u16* lB1 = &Bs[c1 * 8];

  // reader fragment offsets (A-frag: m = lane&15, k = quad*8+j)
  int aoff[4], boff[4];
  const int lq = (quad ^ (mrow & 3)) * 8;
#pragma unroll
  for (int t = 0; t < 4; ++t) {
    aoff[t] = (wm * 64 + t * 16 + mrow) * 32 + lq;
    boff[t] = (wn * 64 + t * 16 + mrow) * 32 + lq;
  }

  for (int k0 = 0; k0 < K; k0 += 32) {
    __syncthreads();  // previous iter's LDS reads done before overwrite
    load_lds16(a0 + k0, lA0);
    load_lds16(a1 + k0, lA1);
    load_lds16(b0 + k0, lB0);
    load_lds16(b1 + k0, lB1);
    __syncthreads();  // compiler drains vmcnt before barrier
    bf16x8 af[4], bfr[4];
#pragma unroll
    for (int t = 0; t < 4; ++t) {
      af[t] = *(const bf16x8*)&As[aoff[t]];
      bfr[t] = *(const bf16x8*)&Bs[boff[t]];
    }
#pragma unroll
    for (int i = 0; i < 4; ++i)
#pragma unroll
      for (int j = 0; j < 4; ++j)
        acc[i][j] = __builtin_amdgcn_mfma_f32_16x16x32_bf16(af[i], bfr[j], acc[i][j], 0, 0, 0);
  }
}

// GEMM1: xq[8192,1024] x wcat[6144,1024]^T -> up (cols 0..3071) / gate->gh (cols 3072..)
// raw fp32 acc -> amax atomics (slot1=up, slot2=gate) -> bf16 store.
__global__ void __launch_bounds__(256) kgemm1(const u16* __restrict__ xq,
                                              const u16* __restrict__ wcat,
                                              u16* __restrict__ up, u16* __restrict__ gh,
                                              u32* __restrict__ scal) {
  const int tileN = blockIdx.x * 128;
  const int tileM = blockIdx.y * 128;
  f32x4 acc[4][4];
#pragma unroll
  for (int i = 0; i < 4; ++i)
#pragma unroll
    for (int j = 0; j < 4; ++j) acc[i][j] = (f32x4){0.f, 0.f, 0.f, 0.f};
  gemm_core<H_DIM>(xq + (size_t)tileM * H_DIM, wcat + (size_t)tileN * H_DIM, acc);

  u16* outp;
  int ncol, slot;
  if (tileN < I_DIM) { outp = up; ncol = tileN; slot = 1; }
  else               { outp = gh; ncol = tileN - I_DIM; slot = 2; }

  const int lane = threadIdx.x & 63, wave = threadIdx.x >> 6;
  const int wm = wave >> 1, wn = wave & 1;
  const int rb = (lane >> 4) * 4, cb = lane & 15;  // C/D: row=(l>>4)*4+reg, col=l&15
  float mx = 0.f;
#pragma unroll
  for (int i = 0; i < 4; ++i) {
#pragma unroll
    for (int j = 0; j < 4; ++j) {
      size_t base = (size_t)(tileM + wm * 64 + i * 16 + rb) * I_DIM +
                    (size_t)(ncol + wn * 64 + j * 16 + cb);
#pragma unroll
      for (int r = 0; r < 4; ++r) {
        float v = acc[i][j][r];
        mx = fmaxf(mx, fabsf(v));
        outp[base + (size_t)r * I_DIM] = f2bf(v);
      }
    }
  }
  block_amax_atomic(mx, scal + slot);
}

// GEMM2: oq[8192,3072] x wdq[1024,3072]^T -> out fp32 [8192,1024]
__global__ void __launch_bounds__(256) kgemm2(const u16* __restrict__ oq,
                                              const u16* __restrict__ wdq,
                                              float* __restrict__ out) {
  const int tileN = blockIdx.x * 128;
  const int tileM = blockIdx.y * 128;
  f32x4 acc[4][4];
#pragma unroll
  for (int i = 0; i < 4; ++i)
#pragma unroll
    for (int j = 0; j < 4; ++j) acc[i][j] = (f32x4){0.f, 0.f, 0.f, 0.f};
  gemm_core<I_DIM>(oq + (size_t)tileM * I_DIM, wdq + (size_t)tileN * I_DIM, acc);

  const int lane = threadIdx.x & 63, wave = threadIdx.x >> 6;
  const int wm = wave >> 1, wn = wave & 1;
  const int rb = (lane >> 4) * 4, cb = lane & 15;
#pragma unroll
  for (int i = 0; i < 4; ++i) {
#pragma unroll
    for (int j = 0; j < 4; ++j) {
      size_t base = (size_t)(tileM + wm * 64 + i * 16 + rb) * H_DIM +
                    (size_t)(tileN + wn * 64 + j * 16 + cb);
#pragma unroll
      for (int r = 0; r < 4; ++r) out[base + (size_t)r * H_DIM] = acc[i][j][r];
    }
  }
}

// ---------------- elementwise kernels ----------------
__global__ void __launch_bounds__(256) kabsmax(const float4* __restrict__ x, int n4,
                                               u32* __restrict__ slot) {
  float mx = 0.f;
  for (int i = blockIdx.x * blockDim.x + threadIdx.x; i < n4; i += gridDim.x * blockDim.x) {
    float4 v = x[i];
    mx = fmaxf(fmaxf(fabsf(v.x), fabsf(v.y)), fmaxf(fmaxf(fabsf(v.z), fabsf(v.w)), mx));
  }
  block_amax_atomic(mx, slot);
}

// LPBQ dequant: flat 32-element blocks (I,K both %32==0 so rows never split).
// 8 lanes per block, float4/lane, shfl-xor max, fp32-exact qdq, bf16 store.
// wcat rows 0..3071 = w_up, 3072..6143 = w_gate; wdq = w_down.
__global__ void __launch_bounds__(256) kdequant(const float* __restrict__ wu,
                                                const float* __restrict__ wg,
                                                const float* __restrict__ wdn,
                                                u16* __restrict__ wcat, u16* __restrict__ wdq) {
  const int gid = blockIdx.x * 256 + threadIdx.x;
  const int unit = gid >> 3, l8 = gid & 7;
  const float* src;
  u16* dst;
  int u;
  if (unit < 98304)       { src = wu;  dst = wcat;            u = unit; }
  else if (unit < 196608) { src = wg;  dst = wcat + 3145728;  u = unit - 98304; }
  else                    { src = wdn; dst = wdq;             u = unit - 196608; }
  const size_t off = (size_t)u * 32 + (size_t)l8 * 4;
  float4 v = *(const float4*)(src + off);
  float m = fmaxf(fmaxf(fabsf(v.x), fabsf(v.y)), fmaxf(fabsf(v.z), fabsf(v.w)));
  m = fmaxf(m, __shfl_xor(m, 1));
  m = fmaxf(m, __shfl_xor(m, 2));
  m = fmaxf(m, __shfl_xor(m, 4));
  const float s = fmaxf(m / 7.0f, 1e-12f);
  float vv[4] = {v.x, v.y, v.z, v.w};
  u16 o[4];
#pragma unroll
  for (int e = 0; e < 4; ++e) {
    float q = rintf(vv[e] / s);
    q = fminf(fmaxf(q, -8.f), 7.f);
    o[e] = f2bf(q * s);
  }
  *(ushort4*)(dst + off) = make_ushort4(o[0], o[1], o[2], o[3]);
}

__global__ void __launch_bounds__(256) kqdqx(const float4* __restrict__ x,
                                             ushort4* __restrict__ xq,
                                             const u32* __restrict__ scal) {
  const float s = scale_from(scal[0]);
  const int i = blockIdx.x * 256 + threadIdx.x;
  float4 v = x[i];
  ushort4 o;
  o.x = f2bf(qdq16(v.x, s));
  o.y = f2bf(qdq16(v.y, s));
  o.z = f2bf(qdq16(v.z, s));
  o.w = f2bf(qdq16(v.w, s));
  xq[i] = o;
}

// gate(raw) -> h = qdq(gate)*fixed_u16(sigmoid(qdq(gate))), in place; amax(h)->scal[3]
__global__ void __launch_bounds__(256) kswiglu(uint4* __restrict__ gh, u32* __restrict__ scal) {
  const float sg = scale_from(scal[2]);
  const int i = blockIdx.x * 256 + threadIdx.x;
  union { uint4 v; u16 us[8]; } u;
  u.v = gh[i];
  float mx = 0.f;
#pragma unroll
  for (int e = 0; e < 8; ++e) {
    float g = qdq16(bf2f(u.us[e]), sg);
    float sig = 1.f / (1.f + expf(-g));
    float sq = fminf(fmaxf(rintf(sig * 65536.f), 0.f), 65535.f) * (1.f / 65536.f);
    float h = g * sq;
    mx = fmaxf(mx, fabsf(h));
    u.us[e] = f2bf(h);
  }
  gh[i] = u.v;
  block_amax_atomic(mx, scal + 3);
}

// o = qdq(h)*qdq(up), in place over h; amax(o)->scal[4]
__global__ void __launch_bounds__(256) kmulo(uint4* __restrict__ gh, const uint4* __restrict__ up,
                                             u32* __restrict__ scal) {
  const float sh = scale_from(scal[3]);
  const float su = scale_from(scal[1]);
  const int i = blockIdx.x * 256 + threadIdx.x;
  union { uint4 v; u16 us[8]; } a, b;
  a.v = gh[i];
  b.v = up[i];
  float mx = 0.f;
#pragma unroll
  for (int e = 0; e < 8; ++e) {
    float o = qdq16(bf2f(a.us[e]), sh) * qdq16(bf2f(b.us[e]), su);
    mx = fmaxf(mx, fabsf(o));
    a.us[e] = f2bf(o);
  }
  gh[i] = a.v;
  block_amax_atomic(mx, scal + 4);
}

__global__ void __launch_bounds__(256) kqdqo(uint4* __restrict__ gh, const u32* __restrict__ scal) {
  const float so = scale_from(scal[4]);
  const int i = blockIdx.x * 256 + threadIdx.x;
  union { uint4 v; u16 us[8]; } u;
  u.v = gh[i];
#pragma unroll
  for (int e = 0; e < 8; ++e) u.us[e] = f2bf(qdq16(bf2f(u.us[e]), so));
  gh[i] = u.v;
}

extern "C" void kernel_launch(void* const* d_in, const int* in_sizes, int n_in,
                              void* d_out, int out_size, void* d_ws, size_t ws_size,
                              hipStream_t stream) {
  (void)in_sizes; (void)n_in; (void)out_size; (void)ws_size;
  const float* x   = (const float*)d_in[0];
  const float* wg  = (const float*)d_in[1];  // NOTE: setup dict order: x, w_gate, w_up, w_down
  const float* wu  = (const float*)d_in[2];
  const float* wdn = (const float*)d_in[3];
  float* out = (float*)d_out;
  char* ws = (char*)d_ws;

  // ws layout (needs ~136.3 MB):
  u32* scal = (u32*)ws;  // [0]=amax_x [1]=amax_up [2]=amax_gate [3]=amax_h [4]=amax_o
  u16* xq   = (u16*)(ws + 256);                     // 8192*1024
  u16* wcat = xq + (size_t)M_ROWS * H_DIM;          // 6144*1024 (up rows then gate rows)
  u16* wdq  = wcat + (size_t)2 * I_DIM * H_DIM;     // 1024*3072
  u16* up   = wdq + (size_t)H_DIM * I_DIM;          // 8192*3072
  u16* gh   = up + (size_t)M_ROWS * I_DIM;          // 8192*3072 (gate -> h -> o -> oq)

  hipMemsetAsync(scal, 0, 256, stream);
  kabsmax<<<1024, 256, 0, stream>>>((const float4*)x, (M_ROWS * H_DIM) / 4, scal + 0);
  kdequant<<<9216, 256, 0, stream>>>(wu, wg, wdn, wcat, wdq);
  kqdqx<<<(M_ROWS * H_DIM) / 4 / 256, 256, 0, stream>>>((const float4*)x, (ushort4*)xq, scal);
  kgemm1<<<dim3(48, 64), 256, 0, stream>>>(xq, wcat, up, gh, scal);
  kswiglu<<<12288, 256, 0, stream>>>((uint4*)gh, scal);
  kmulo<<<12288, 256, 0, stream>>>((uint4*)gh, (const uint4*)up, scal);
  kqdqo<<<12288, 256, 0, stream>>>((uint4*)gh, scal);
  kgemm2<<<dim3(8, 64), 256, 0, stream>>>(gh, wdq, out);
}

// Round 2
// 375.981 us; speedup vs baseline: 1.7157x; 1.7157x over previous
//
#include <hip/hip_runtime.h>
#include <hip/hip_bf16.h>
#include <stdint.h>

// Qwen3 MLP with QDQ fake-quant, MI355X gfx950.
// M=8192 (B*S), H=1024, I=3072.
// R2: amax atomics were the bottleneck (12288 same-address atomicMax = 147us
// per elementwise kernel). Now: grid-stride (<=2048 blocks) + 16 sub-slot
// atomics on distinct 64B lines; readers max over sub-slots. qdq uses
// reciprocal-multiply instead of fp div; swiglu uses __expf + native rcp.

#define M_ROWS 8192
#define H_DIM 1024
#define I_DIM 3072

typedef unsigned short u16;
typedef unsigned int u32;
typedef __attribute__((ext_vector_type(8))) short bf16x8;
typedef __attribute__((ext_vector_type(4))) float f32x4;

__device__ __forceinline__ float bf2f(u16 v) { return __uint_as_float(((u32)v) << 16); }
__device__ __forceinline__ u16 f2bf(float f) {
  u32 u = __float_as_uint(f);
  u32 r = (u + 0x7fffu + ((u >> 16) & 1u)) >> 16;
  return (u16)r;
}
// 16-bit symmetric fake quant-dequant via reciprocal multiply
__device__ __forceinline__ float qdq16i(float x, float inv, float s) {
  float q = rintf(x * inv);
  q = fminf(fmaxf(q, -32768.f), 32767.f);
  return q * s;
}

// scal layout: u32[16][16]; sub-slot j of slot s at scal[j*16 + s].
// Each j-row is its own 64B cache line -> 16-way spread of atomic contention.
__device__ __forceinline__ float scale_read(const u32* __restrict__ scal, int s) {
  u32 m = 0;
#pragma unroll
  for (int j = 0; j < 16; ++j) m = max(m, scal[j * 16 + s]);
  return fmaxf(__uint_as_float(m) / 32767.f, 1e-12f);
}

__device__ __forceinline__ void load_lds16(const u16* g, u16* lds) {
  __builtin_amdgcn_global_load_lds(
      (const __attribute__((address_space(1))) u32*)g,
      (__attribute__((address_space(3))) u32*)lds, 16, 0, 0);
}

// block = 256 threads (4 waves). Wave shuffle-max then LDS then one atomicMax
// to sub-slot (blockIdx&15) of slot s.
__device__ __forceinline__ void block_amax_atomic(float mx, u32* scal, int s) {
#pragma unroll
  for (int off = 32; off; off >>= 1) mx = fmaxf(mx, __shfl_xor(mx, off));
  __shared__ float red[4];
  const int lane = threadIdx.x & 63, wave = threadIdx.x >> 6;
  if (lane == 0) red[wave] = mx;
  __syncthreads();
  if (threadIdx.x == 0) {
    float m = fmaxf(fmaxf(red[0], red[1]), fmaxf(red[2], red[3]));
    atomicMax(scal + (blockIdx.x & 15) * 16 + s, __float_as_uint(m));
  }
}

// ---------------- GEMM core (m97 structure) ----------------
// C[m,n] = sum_k A[m,k]*B[n,k]; A,B row-major with row stride K (bf16 bits).
// 128x128 tile, BK=32, 4 waves each computing 64x64 via 4x4 MFMA 16x16x32.
template <int K>
__device__ __forceinline__ void gemm_core(const u16* __restrict__ Ablk,
                                          const u16* __restrict__ Bblk,
                                          f32x4 acc[4][4]) {
  __shared__ __align__(16) u16 As[128 * 32];
  __shared__ __align__(16) u16 Bs[128 * 32];
  const int tid = threadIdx.x;
  const int lane = tid & 63, wave = tid >> 6;
  const int wm = wave >> 1, wn = wave & 1;
  const int quad = lane >> 4, mrow = lane & 15;

  const int c0 = tid, c1 = tid + 256;
  const int r0 = c0 >> 2, g0 = ((c0 & 3) ^ (r0 & 3)) * 8;
  const int r1 = c1 >> 2, g1 = ((c1 & 3) ^ (r1 & 3)) * 8;
  const u16* a0 = Ablk + (size_t)r0 * K + g0;
  const u16* a1 = Ablk + (size_t)r1 * K + g1;
  const u16* b0 = Bblk + (size_t)r0 * K + g0;
  const u16* b1 = Bblk + (size_t)r1 * K + g1;
  u16* lA0 = &As[c0 * 8];
  u16* lA1 = &As[c1 * 8];
  u16* lB0 = &Bs[c0 * 8];
  u16* lB1 = &Bs[c1 * 8];

  int aoff[4], boff[4];
  const int lq = (quad ^ (mrow & 3)) * 8;
#pragma unroll
  for (int t = 0; t < 4; ++t) {
    aoff[t] = (wm * 64 + t * 16 + mrow) * 32 + lq;
    boff[t] = (wn * 64 + t * 16 + mrow) * 32 + lq;
  }

  for (int k0 = 0; k0 < K; k0 += 32) {
    __syncthreads();
    load_lds16(a0 + k0, lA0);
    load_lds16(a1 + k0, lA1);
    load_lds16(b0 + k0, lB0);
    load_lds16(b1 + k0, lB1);
    __syncthreads();
    bf16x8 af[4], bfr[4];
#pragma unroll
    for (int t = 0; t < 4; ++t) {
      af[t] = *(const bf16x8*)&As[aoff[t]];
      bfr[t] = *(const bf16x8*)&Bs[boff[t]];
    }
#pragma unroll
    for (int i = 0; i < 4; ++i)
#pragma unroll
      for (int j = 0; j < 4; ++j)
        acc[i][j] = __builtin_amdgcn_mfma_f32_16x16x32_bf16(af[i], bfr[j], acc[i][j], 0, 0, 0);
  }
}

// GEMM1: xq[8192,1024] x wcat[6144,1024]^T -> up (cols 0..3071) / gate->gh
__global__ void __launch_bounds__(256) kgemm1(const u16* __restrict__ xq,
                                              const u16* __restrict__ wcat,
                                              u16* __restrict__ up, u16* __restrict__ gh,
                                              u32* __restrict__ scal) {
  const int tileN = blockIdx.x * 128;
  const int tileM = blockIdx.y * 128;
  f32x4 acc[4][4];
#pragma unroll
  for (int i = 0; i < 4; ++i)
#pragma unroll
    for (int j = 0; j < 4; ++j) acc[i][j] = (f32x4){0.f, 0.f, 0.f, 0.f};
  gemm_core<H_DIM>(xq + (size_t)tileM * H_DIM, wcat + (size_t)tileN * H_DIM, acc);

  u16* outp;
  int ncol, slot;
  if (tileN < I_DIM) { outp = up; ncol = tileN; slot = 1; }
  else               { outp = gh; ncol = tileN - I_DIM; slot = 2; }

  const int lane = threadIdx.x & 63, wave = threadIdx.x >> 6;
  const int wm = wave >> 1, wn = wave & 1;
  const int rb = (lane >> 4) * 4, cb = lane & 15;  // C/D: row=(l>>4)*4+reg, col=l&15
  float mx = 0.f;
#pragma unroll
  for (int i = 0; i < 4; ++i) {
#pragma unroll
    for (int j = 0; j < 4; ++j) {
      size_t base = (size_t)(tileM + wm * 64 + i * 16 + rb) * I_DIM +
                    (size_t)(ncol + wn * 64 + j * 16 + cb);
#pragma unroll
      for (int r = 0; r < 4; ++r) {
        float v = acc[i][j][r];
        mx = fmaxf(mx, fabsf(v));
        outp[base + (size_t)r * I_DIM] = f2bf(v);
      }
    }
  }
  block_amax_atomic(mx, scal, slot);
}

// GEMM2: oq[8192,3072] x wdq[1024,3072]^T -> out fp32 [8192,1024]
__global__ void __launch_bounds__(256) kgemm2(const u16* __restrict__ oq,
                                              const u16* __restrict__ wdq,
                                              float* __restrict__ out) {
  const int tileN = blockIdx.x * 128;
  const int tileM = blockIdx.y * 128;
  f32x4 acc[4][4];
#pragma unroll
  for (int i = 0; i < 4; ++i)
#pragma unroll
    for (int j = 0; j < 4; ++j) acc[i][j] = (f32x4){0.f, 0.f, 0.f, 0.f};
  gemm_core<I_DIM>(oq + (size_t)tileM * I_DIM, wdq + (size_t)tileN * I_DIM, acc);

  const int lane = threadIdx.x & 63, wave = threadIdx.x >> 6;
  const int wm = wave >> 1, wn = wave & 1;
  const int rb = (lane >> 4) * 4, cb = lane & 15;
#pragma unroll
  for (int i = 0; i < 4; ++i) {
#pragma unroll
    for (int j = 0; j < 4; ++j) {
      size_t base = (size_t)(tileM + wm * 64 + i * 16 + rb) * H_DIM +
                    (size_t)(tileN + wn * 64 + j * 16 + cb);
#pragma unroll
      for (int r = 0; r < 4; ++r) out[base + (size_t)r * H_DIM] = acc[i][j][r];
    }
  }
}

// ---------------- elementwise kernels ----------------
__global__ void __launch_bounds__(256) kabsmax(const float4* __restrict__ x, int n4,
                                               u32* __restrict__ scal) {
  float mx = 0.f;
  for (int i = blockIdx.x * blockDim.x + threadIdx.x; i < n4; i += gridDim.x * blockDim.x) {
    float4 v = x[i];
    mx = fmaxf(fmaxf(fabsf(v.x), fabsf(v.y)), fmaxf(fmaxf(fabsf(v.z), fabsf(v.w)), mx));
  }
  block_amax_atomic(mx, scal, 0);
}

// LPBQ dequant: flat 32-element blocks; 8 lanes/block, float4/lane.
__global__ void __launch_bounds__(256) kdequant(const float* __restrict__ wu,
                                                const float* __restrict__ wg,
                                                const float* __restrict__ wdn,
                                                u16* __restrict__ wcat, u16* __restrict__ wdq) {
  const int gid = blockIdx.x * 256 + threadIdx.x;
  const int unit = gid >> 3, l8 = gid & 7;
  const float* src;
  u16* dst;
  int u;
  if (unit < 98304)       { src = wu;  dst = wcat;            u = unit; }
  else if (unit < 196608) { src = wg;  dst = wcat + 3145728;  u = unit - 98304; }
  else                    { src = wdn; dst = wdq;             u = unit - 196608; }
  const size_t off = (size_t)u * 32 + (size_t)l8 * 4;
  float4 v = *(const float4*)(src + off);
  float m = fmaxf(fmaxf(fabsf(v.x), fabsf(v.y)), fmaxf(fabsf(v.z), fabsf(v.w)));
  m = fmaxf(m, __shfl_xor(m, 1));
  m = fmaxf(m, __shfl_xor(m, 2));
  m = fmaxf(m, __shfl_xor(m, 4));
  const float s = fmaxf(m / 7.0f, 1e-12f);
  const float inv = 1.0f / s;
  float vv[4] = {v.x, v.y, v.z, v.w};
  u16 o[4];
#pragma unroll
  for (int e = 0; e < 4; ++e) {
    float q = rintf(vv[e] * inv);
    q = fminf(fmaxf(q, -8.f), 7.f);
    o[e] = f2bf(q * s);
  }
  *(ushort4*)(dst + off) = make_ushort4(o[0], o[1], o[2], o[3]);
}

__global__ void __launch_bounds__(256) kqdqx(const float4* __restrict__ x,
                                             ushort4* __restrict__ xq,
                                             const u32* __restrict__ scal) {
  const float s = scale_read(scal, 0);
  const float inv = 1.0f / s;
  const int i = blockIdx.x * 256 + threadIdx.x;
  float4 v = x[i];
  ushort4 o;
  o.x = f2bf(qdq16i(v.x, inv, s));
  o.y = f2bf(qdq16i(v.y, inv, s));
  o.z = f2bf(qdq16i(v.z, inv, s));
  o.w = f2bf(qdq16i(v.w, inv, s));
  xq[i] = o;
}

#define GH4 ((M_ROWS * I_DIM) / 8)
#define EW_BLOCKS 2048

// gate(raw) -> h = qdq(gate)*fixed_u16(sigmoid(qdq(gate))), in place; amax(h)->slot3
__global__ void __launch_bounds__(256) kswiglu(uint4* __restrict__ gh, u32* __restrict__ scal) {
  const float sg = scale_read(scal, 2);
  const float inv = 1.0f / sg;
  float mx = 0.f;
  for (int i = blockIdx.x * 256 + threadIdx.x; i < GH4; i += EW_BLOCKS * 256) {
    union { uint4 v; u16 us[8]; } u;
    u.v = gh[i];
#pragma unroll
    for (int e = 0; e < 8; ++e) {
      float g = qdq16i(bf2f(u.us[e]), inv, sg);
      float sig = __builtin_amdgcn_rcpf(1.f + __expf(-g));
      float sq = fminf(fmaxf(rintf(sig * 65536.f), 0.f), 65535.f) * (1.f / 65536.f);
      float h = g * sq;
      mx = fmaxf(mx, fabsf(h));
      u.us[e] = f2bf(h);
    }
    gh[i] = u.v;
  }
  block_amax_atomic(mx, scal, 3);
}

// o = qdq(h)*qdq(up), in place over h; amax(o)->slot4
__global__ void __launch_bounds__(256) kmulo(uint4* __restrict__ gh, const uint4* __restrict__ up,
                                             u32* __restrict__ scal) {
  const float sh = scale_read(scal, 3);
  const float su = scale_read(scal, 1);
  const float ih = 1.0f / sh, iu = 1.0f / su;
  float mx = 0.f;
  for (int i = blockIdx.x * 256 + threadIdx.x; i < GH4; i += EW_BLOCKS * 256) {
    union { uint4 v; u16 us[8]; } a, b;
    a.v = gh[i];
    b.v = up[i];
#pragma unroll
    for (int e = 0; e < 8; ++e) {
      float o = qdq16i(bf2f(a.us[e]), ih, sh) * qdq16i(bf2f(b.us[e]), iu, su);
      mx = fmaxf(mx, fabsf(o));
      a.us[e] = f2bf(o);
    }
    gh[i] = a.v;
  }
  block_amax_atomic(mx, scal, 4);
}

__global__ void __launch_bounds__(256) kqdqo(uint4* __restrict__ gh, const u32* __restrict__ scal) {
  const float so = scale_read(scal, 4);
  const float inv = 1.0f / so;
  const int i = blockIdx.x * 256 + threadIdx.x;
  union { uint4 v; u16 us[8]; } u;
  u.v = gh[i];
#pragma unroll
  for (int e = 0; e < 8; ++e) u.us[e] = f2bf(qdq16i(bf2f(u.us[e]), inv, so));
  gh[i] = u.v;
}

extern "C" void kernel_launch(void* const* d_in, const int* in_sizes, int n_in,
                              void* d_out, int out_size, void* d_ws, size_t ws_size,
                              hipStream_t stream) {
  (void)in_sizes; (void)n_in; (void)out_size; (void)ws_size;
  const float* x   = (const float*)d_in[0];
  const float* wg  = (const float*)d_in[1];
  const float* wu  = (const float*)d_in[2];
  const float* wdn = (const float*)d_in[3];
  float* out = (float*)d_out;
  char* ws = (char*)d_ws;

  u32* scal = (u32*)ws;  // u32[16][16]: sub-slot j of slot s at [j*16+s]
  u16* xq   = (u16*)(ws + 1024);                    // 8192*1024
  u16* wcat = xq + (size_t)M_ROWS * H_DIM;          // 6144*1024
  u16* wdq  = wcat + (size_t)2 * I_DIM * H_DIM;     // 1024*3072
  u16* up   = wdq + (size_t)H_DIM * I_DIM;          // 8192*3072
  u16* gh   = up + (size_t)M_ROWS * I_DIM;          // 8192*3072

  hipMemsetAsync(scal, 0, 1024, stream);
  kabsmax<<<1024, 256, 0, stream>>>((const float4*)x, (M_ROWS * H_DIM) / 4, scal);
  kdequant<<<9216, 256, 0, stream>>>(wu, wg, wdn, wcat, wdq);
  kqdqx<<<(M_ROWS * H_DIM) / 4 / 256, 256, 0, stream>>>((const float4*)x, (ushort4*)xq, scal);
  kgemm1<<<dim3(48, 64), 256, 0, stream>>>(xq, wcat, up, gh, scal);
  kswiglu<<<EW_BLOCKS, 256, 0, stream>>>((uint4*)gh, scal);
  kmulo<<<EW_BLOCKS, 256, 0, stream>>>((uint4*)gh, (const uint4*)up, scal);
  kqdqo<<<(M_ROWS * I_DIM) / 8 / 256, 256, 0, stream>>>((uint4*)gh, scal);
  kgemm2<<<dim3(8, 64), 256, 0, stream>>>(gh, wdq, out);
}

// Round 3
// 375.136 us; speedup vs baseline: 1.7195x; 1.0023x over previous
//
#include <hip/hip_runtime.h>
#include <hip/hip_bf16.h>
#include <stdint.h>

// Qwen3 MLP with QDQ fake-quant, MI355X gfx950.
// M=8192 (B*S), H=1024, I=3072.
// R3: (1) LDS swizzle (row>>1)&3 -> 2-way (free) instead of 4-way conflicts;
// (2) kgemm1 epilogue LDS-transpose -> uint4 stores; (3) kswiglu read-only
// (amax only), kmulo recomputes h from gate bit-exactly (saves 75MB write).

#define M_ROWS 8192
#define H_DIM 1024
#define I_DIM 3072

typedef unsigned short u16;
typedef unsigned int u32;
typedef __attribute__((ext_vector_type(8))) short bf16x8;
typedef __attribute__((ext_vector_type(4))) float f32x4;

__device__ __forceinline__ float bf2f(u16 v) { return __uint_as_float(((u32)v) << 16); }
__device__ __forceinline__ u16 f2bf(float f) {
  u32 u = __float_as_uint(f);
  u32 r = (u + 0x7fffu + ((u >> 16) & 1u)) >> 16;
  return (u16)r;
}
__device__ __forceinline__ float qdq16i(float x, float inv, float s) {
  float q = rintf(x * inv);
  q = fminf(fmaxf(q, -32768.f), 32767.f);
  return q * s;
}

// scal: u32[16][16]; sub-slot j of slot s at scal[j*16+s] (16 distinct 64B lines)
__device__ __forceinline__ float scale_read(const u32* __restrict__ scal, int s) {
  u32 m = 0;
#pragma unroll
  for (int j = 0; j < 16; ++j) m = max(m, scal[j * 16 + s]);
  return fmaxf(__uint_as_float(m) / 32767.f, 1e-12f);
}

__device__ __forceinline__ void load_lds16(const u16* g, u16* lds) {
  __builtin_amdgcn_global_load_lds(
      (const __attribute__((address_space(1))) u32*)g,
      (__attribute__((address_space(3))) u32*)lds, 16, 0, 0);
}

__device__ __forceinline__ void block_amax_atomic(float mx, u32* scal, int s) {
#pragma unroll
  for (int off = 32; off; off >>= 1) mx = fmaxf(mx, __shfl_xor(mx, off));
  __shared__ float red[4];
  const int lane = threadIdx.x & 63, wave = threadIdx.x >> 6;
  if (lane == 0) red[wave] = mx;
  __syncthreads();
  if (threadIdx.x == 0) {
    float m = fmaxf(fmaxf(red[0], red[1]), fmaxf(red[2], red[3]));
    atomicMax(scal + (blockIdx.x & 15) * 16 + s, __float_as_uint(m));
  }
}

// ---------------- GEMM core ----------------
// C[m,n] = sum_k A[m,k]*B[n,k]; A,B row-major, row stride K (bf16 bits).
// 128x128 tile, BK=32, 4 waves each 64x64 via 4x4 MFMA 16x16x32.
// LDS chunk position q of row r holds global granule q^((r>>1)&3):
// read bank-start depends on (r&1, (r>>1)&3) -> 8 groups over 16 rows -> 2-way (free).
template <int K>
__device__ __forceinline__ void gemm_core(const u16* __restrict__ Ablk,
                                          const u16* __restrict__ Bblk,
                                          f32x4 acc[4][4], u16* smem) {
  u16* As = smem;          // 128*32
  u16* Bs = smem + 4096;   // 128*32
  const int tid = threadIdx.x;
  const int lane = tid & 63, wave = tid >> 6;
  const int wm = wave >> 1, wn = wave & 1;
  const int quad = lane >> 4, mrow = lane & 15;

  const int c0 = tid, c1 = tid + 256;
  const int r0 = c0 >> 2, g0 = ((c0 & 3) ^ ((r0 >> 1) & 3)) * 8;
  const int r1 = c1 >> 2, g1 = ((c1 & 3) ^ ((r1 >> 1) & 3)) * 8;
  const u16* a0 = Ablk + (size_t)r0 * K + g0;
  const u16* a1 = Ablk + (size_t)r1 * K + g1;
  const u16* b0 = Bblk + (size_t)r0 * K + g0;
  const u16* b1 = Bblk + (size_t)r1 * K + g1;
  u16* lA0 = &As[c0 * 8];
  u16* lA1 = &As[c1 * 8];
  u16* lB0 = &Bs[c0 * 8];
  u16* lB1 = &Bs[c1 * 8];

  int aoff[4], boff[4];
  const int lq = (quad ^ ((mrow >> 1) & 3)) * 8;
#pragma unroll
  for (int t = 0; t < 4; ++t) {
    aoff[t] = (wm * 64 + t * 16 + mrow) * 32 + lq;
    boff[t] = (wn * 64 + t * 16 + mrow) * 32 + lq;
  }

  for (int k0 = 0; k0 < K; k0 += 32) {
    __syncthreads();
    load_lds16(a0 + k0, lA0);
    load_lds16(a1 + k0, lA1);
    load_lds16(b0 + k0, lB0);
    load_lds16(b1 + k0, lB1);
    __syncthreads();
    bf16x8 af[4], bfr[4];
#pragma unroll
    for (int t = 0; t < 4; ++t) {
      af[t] = *(const bf16x8*)&As[aoff[t]];
      bfr[t] = *(const bf16x8*)&Bs[boff[t]];
    }
#pragma unroll
    for (int i = 0; i < 4; ++i)
#pragma unroll
      for (int j = 0; j < 4; ++j)
        acc[i][j] = __builtin_amdgcn_mfma_f32_16x16x32_bf16(af[i], bfr[j], acc[i][j], 0, 0, 0);
  }
}

// GEMM1: xq[8192,1024] x wcat[6144,1024]^T -> up (tileN<3072) / gate->gh
__global__ void __launch_bounds__(256) kgemm1(const u16* __restrict__ xq,
                                              const u16* __restrict__ wcat,
                                              u16* __restrict__ up, u16* __restrict__ gh,
                                              u32* __restrict__ scal) {
  __shared__ __align__(16) u16 smem[8192];
  const int tileN = blockIdx.x * 128;
  const int tileM = blockIdx.y * 128;
  f32x4 acc[4][4];
#pragma unroll
  for (int i = 0; i < 4; ++i)
#pragma unroll
    for (int j = 0; j < 4; ++j) acc[i][j] = (f32x4){0.f, 0.f, 0.f, 0.f};
  gemm_core<H_DIM>(xq + (size_t)tileM * H_DIM, wcat + (size_t)tileN * H_DIM, acc, smem);

  u16* outp;
  int ncol, slot;
  if (tileN < I_DIM) { outp = up; ncol = tileN; slot = 1; }
  else               { outp = gh; ncol = tileN - I_DIM; slot = 2; }

  const int lane = threadIdx.x & 63, wave = threadIdx.x >> 6;
  const int wm = wave >> 1, wn = wave & 1;
  const int rb = (lane >> 4) * 4, cb = lane & 15;  // C/D: row=(l>>4)*4+reg, col=l&15
  const int erow = lane >> 2, echk = lane & 3;
  u16* wbase = smem + wave * 1152;                 // 16 rows * 72 (pad 8 -> 144B stride)
  const u16* rbase = smem + wave * 1152 + erow * 72;
  float mx = 0.f;
#pragma unroll
  for (int i = 0; i < 4; ++i) {
    __syncthreads();
#pragma unroll
    for (int j = 0; j < 4; ++j)
#pragma unroll
      for (int r = 0; r < 4; ++r) {
        float v = acc[i][j][r];
        mx = fmaxf(mx, fabsf(v));
        wbase[(rb + r) * 72 + j * 16 + cb] = f2bf(v);
      }
    __syncthreads();
    uint4 v0 = *(const uint4*)(rbase + echk * 8);
    uint4 v1 = *(const uint4*)(rbase + (echk + 4) * 8);
    size_t grow = (size_t)(tileM + wm * 64 + i * 16 + erow) * I_DIM + (ncol + wn * 64);
    *(uint4*)(outp + grow + echk * 8) = v0;
    *(uint4*)(outp + grow + (echk + 4) * 8) = v1;
  }
  block_amax_atomic(mx, scal, slot);
}

// GEMM2: oq[8192,3072] x wdq[1024,3072]^T -> out fp32 [8192,1024]
__global__ void __launch_bounds__(256) kgemm2(const u16* __restrict__ oq,
                                              const u16* __restrict__ wdq,
                                              float* __restrict__ out) {
  __shared__ __align__(16) u16 smem[8192];
  const int tileN = blockIdx.x * 128;
  const int tileM = blockIdx.y * 128;
  f32x4 acc[4][4];
#pragma unroll
  for (int i = 0; i < 4; ++i)
#pragma unroll
    for (int j = 0; j < 4; ++j) acc[i][j] = (f32x4){0.f, 0.f, 0.f, 0.f};
  gemm_core<I_DIM>(oq + (size_t)tileM * I_DIM, wdq + (size_t)tileN * I_DIM, acc, smem);

  const int lane = threadIdx.x & 63, wave = threadIdx.x >> 6;
  const int wm = wave >> 1, wn = wave & 1;
  const int rb = (lane >> 4) * 4, cb = lane & 15;
#pragma unroll
  for (int i = 0; i < 4; ++i) {
#pragma unroll
    for (int j = 0; j < 4; ++j) {
      size_t base = (size_t)(tileM + wm * 64 + i * 16 + rb) * H_DIM +
                    (size_t)(tileN + wn * 64 + j * 16 + cb);
#pragma unroll
      for (int r = 0; r < 4; ++r) out[base + (size_t)r * H_DIM] = acc[i][j][r];
    }
  }
}

// ---------------- elementwise kernels ----------------
__global__ void __launch_bounds__(256) kabsmax(const float4* __restrict__ x, int n4,
                                               u32* __restrict__ scal) {
  float mx = 0.f;
  for (int i = blockIdx.x * blockDim.x + threadIdx.x; i < n4; i += gridDim.x * blockDim.x) {
    float4 v = x[i];
    mx = fmaxf(fmaxf(fabsf(v.x), fabsf(v.y)), fmaxf(fmaxf(fabsf(v.z), fabsf(v.w)), mx));
  }
  block_amax_atomic(mx, scal, 0);
}

__global__ void __launch_bounds__(256) kdequant(const float* __restrict__ wu,
                                                const float* __restrict__ wg,
                                                const float* __restrict__ wdn,
                                                u16* __restrict__ wcat, u16* __restrict__ wdq) {
  const int gid = blockIdx.x * 256 + threadIdx.x;
  const int unit = gid >> 3, l8 = gid & 7;
  const float* src;
  u16* dst;
  int u;
  if (unit < 98304)       { src = wu;  dst = wcat;            u = unit; }
  else if (unit < 196608) { src = wg;  dst = wcat + 3145728;  u = unit - 98304; }
  else                    { src = wdn; dst = wdq;             u = unit - 196608; }
  const size_t off = (size_t)u * 32 + (size_t)l8 * 4;
  float4 v = *(const float4*)(src + off);
  float m = fmaxf(fmaxf(fabsf(v.x), fabsf(v.y)), fmaxf(fabsf(v.z), fabsf(v.w)));
  m = fmaxf(m, __shfl_xor(m, 1));
  m = fmaxf(m, __shfl_xor(m, 2));
  m = fmaxf(m, __shfl_xor(m, 4));
  const float s = fmaxf(m / 7.0f, 1e-12f);
  const float inv = 1.0f / s;
  float vv[4] = {v.x, v.y, v.z, v.w};
  u16 o[4];
#pragma unroll
  for (int e = 0; e < 4; ++e) {
    float q = rintf(vv[e] * inv);
    q = fminf(fmaxf(q, -8.f), 7.f);
    o[e] = f2bf(q * s);
  }
  *(ushort4*)(dst + off) = make_ushort4(o[0], o[1], o[2], o[3]);
}

__global__ void __launch_bounds__(256) kqdqx(const float4* __restrict__ x,
                                             ushort4* __restrict__ xq,
                                             const u32* __restrict__ scal) {
  const float s = scale_read(scal, 0);
  const float inv = 1.0f / s;
  const int i = blockIdx.x * 256 + threadIdx.x;
  float4 v = x[i];
  ushort4 o;
  o.x = f2bf(qdq16i(v.x, inv, s));
  o.y = f2bf(qdq16i(v.y, inv, s));
  o.z = f2bf(qdq16i(v.z, inv, s));
  o.w = f2bf(qdq16i(v.w, inv, s));
  xq[i] = o;
}

#define GH4 ((M_ROWS * I_DIM) / 8)
#define EW_BLOCKS 2048

// read-only: amax over h = qdq(gate)*fixed_u16(sigmoid(qdq(gate))) -> slot3
__global__ void __launch_bounds__(256) kswiglu(const uint4* __restrict__ gh,
                                               u32* __restrict__ scal) {
  const float sg = scale_read(scal, 2);
  const float inv = 1.0f / sg;
  float mx = 0.f;
  for (int i = blockIdx.x * 256 + threadIdx.x; i < GH4; i += EW_BLOCKS * 256) {
    union { uint4 v; u16 us[8]; } u;
    u.v = gh[i];
#pragma unroll
    for (int e = 0; e < 8; ++e) {
      float g = qdq16i(bf2f(u.us[e]), inv, sg);
      float sig = __builtin_amdgcn_rcpf(1.f + __expf(-g));
      float sq = fminf(fmaxf(rintf(sig * 65536.f), 0.f), 65535.f) * (1.f / 65536.f);
      mx = fmaxf(mx, fabsf(g * sq));
    }
  }
  block_amax_atomic(mx, scal, 3);
}

// recompute h from gate (bit-exact vs kswiglu), o = qdq(h)*qdq(up) -> gh; amax(o)->slot4
__global__ void __launch_bounds__(256) kmulo(uint4* __restrict__ gh, const uint4* __restrict__ up,
                                             u32* __restrict__ scal) {
  const float sg = scale_read(scal, 2);
  const float sh = scale_read(scal, 3);
  const float su = scale_read(scal, 1);
  const float ig = 1.0f / sg, ih = 1.0f / sh, iu = 1.0f / su;
  float mx = 0.f;
  for (int i = blockIdx.x * 256 + threadIdx.x; i < GH4; i += EW_BLOCKS * 256) {
    union { uint4 v; u16 us[8]; } a, b;
    a.v = gh[i];
    b.v = up[i];
#pragma unroll
    for (int e = 0; e < 8; ++e) {
      float g = qdq16i(bf2f(a.us[e]), ig, sg);
      float sig = __builtin_amdgcn_rcpf(1.f + __expf(-g));
      float sq = fminf(fmaxf(rintf(sig * 65536.f), 0.f), 65535.f) * (1.f / 65536.f);
      u16 hb = f2bf(g * sq);  // match prior bf16 round-trip of h
      float o = qdq16i(bf2f(hb), ih, sh) * qdq16i(bf2f(b.us[e]), iu, su);
      mx = fmaxf(mx, fabsf(o));
      a.us[e] = f2bf(o);
    }
    gh[i] = a.v;
  }
  block_amax_atomic(mx, scal, 4);
}

__global__ void __launch_bounds__(256) kqdqo(uint4* __restrict__ gh, const u32* __restrict__ scal) {
  const float so = scale_read(scal, 4);
  const float inv = 1.0f / so;
  const int i = blockIdx.x * 256 + threadIdx.x;
  union { uint4 v; u16 us[8]; } u;
  u.v = gh[i];
#pragma unroll
  for (int e = 0; e < 8; ++e) u.us[e] = f2bf(qdq16i(bf2f(u.us[e]), inv, so));
  gh[i] = u.v;
}

extern "C" void kernel_launch(void* const* d_in, const int* in_sizes, int n_in,
                              void* d_out, int out_size, void* d_ws, size_t ws_size,
                              hipStream_t stream) {
  (void)in_sizes; (void)n_in; (void)out_size; (void)ws_size;
  const float* x   = (const float*)d_in[0];
  const float* wg  = (const float*)d_in[1];
  const float* wu  = (const float*)d_in[2];
  const float* wdn = (const float*)d_in[3];
  float* out = (float*)d_out;
  char* ws = (char*)d_ws;

  u32* scal = (u32*)ws;
  u16* xq   = (u16*)(ws + 1024);                    // 8192*1024
  u16* wcat = xq + (size_t)M_ROWS * H_DIM;          // 6144*1024
  u16* wdq  = wcat + (size_t)2 * I_DIM * H_DIM;     // 1024*3072
  u16* up   = wdq + (size_t)H_DIM * I_DIM;          // 8192*3072
  u16* gh   = up + (size_t)M_ROWS * I_DIM;          // 8192*3072

  hipMemsetAsync(scal, 0, 1024, stream);
  kabsmax<<<1024, 256, 0, stream>>>((const float4*)x, (M_ROWS * H_DIM) / 4, scal);
  kdequant<<<9216, 256, 0, stream>>>(wu, wg, wdn, wcat, wdq);
  kqdqx<<<(M_ROWS * H_DIM) / 4 / 256, 256, 0, stream>>>((const float4*)x, (ushort4*)xq, scal);
  kgemm1<<<dim3(48, 64), 256, 0, stream>>>(xq, wcat, up, gh, scal);
  kswiglu<<<EW_BLOCKS, 256, 0, stream>>>((const uint4*)gh, scal);
  kmulo<<<EW_BLOCKS, 256, 0, stream>>>((uint4*)gh, (const uint4*)up, scal);
  kqdqo<<<(M_ROWS * I_DIM) / 8 / 256, 256, 0, stream>>>((uint4*)gh, scal);
  kgemm2<<<dim3(8, 64), 256, 0, stream>>>(gh, wdq, out);
}

// Round 4
// 349.002 us; speedup vs baseline: 1.8483x; 1.0749x over previous
//
#include <hip/hip_runtime.h>
#include <hip/hip_bf16.h>
#include <stdint.h>

// Qwen3 MLP with QDQ fake-quant, MI355X gfx950.
// M=8192 (B*S), H=1024, I=3072.
// R4: all four activation amaxes (up, gate, h, o) computed in kgemm1's
// epilogue using approximate h/o (raw fp32 acc, qdq-snap skipped: scale
// rel-err ~0.2% -> <1e-3 final absmax impact). Each block does gate-pass
// then up-pass for the same (m,n) tile, holding h_approx in a padded LDS
// buffer. kswiglu and kqdqo deleted; kmulo fuses exact h/o/qdq(o) chain.

#define M_ROWS 8192
#define H_DIM 1024
#define I_DIM 3072

typedef unsigned short u16;
typedef unsigned int u32;
typedef __attribute__((ext_vector_type(8))) short bf16x8;
typedef __attribute__((ext_vector_type(4))) float f32x4;

__device__ __forceinline__ float bf2f(u16 v) { return __uint_as_float(((u32)v) << 16); }
__device__ __forceinline__ u16 f2bf(float f) {
  u32 u = __float_as_uint(f);
  u32 r = (u + 0x7fffu + ((u >> 16) & 1u)) >> 16;
  return (u16)r;
}
__device__ __forceinline__ float qdq16i(float x, float inv, float s) {
  float q = rintf(x * inv);
  q = fminf(fmaxf(q, -32768.f), 32767.f);
  return q * s;
}
// fixed u16 sigmoid grid
__device__ __forceinline__ float sigq(float g) {
  float sig = __builtin_amdgcn_rcpf(1.f + __expf(-g));
  return fminf(fmaxf(rintf(sig * 65536.f), 0.f), 65535.f) * (1.f / 65536.f);
}

// scal: u32[16][16]; sub-slot j of slot s at scal[j*16+s] (16 distinct 64B lines)
// slots: 0=x 1=up 2=gate 3=h 4=o
__device__ __forceinline__ float scale_read(const u32* __restrict__ scal, int s) {
  u32 m = 0;
#pragma unroll
  for (int j = 0; j < 16; ++j) m = max(m, scal[j * 16 + s]);
  return fmaxf(__uint_as_float(m) / 32767.f, 1e-12f);
}

__device__ __forceinline__ void load_lds16(const u16* g, u16* lds) {
  __builtin_amdgcn_global_load_lds(
      (const __attribute__((address_space(1))) u32*)g,
      (__attribute__((address_space(3))) u32*)lds, 16, 0, 0);
}

__device__ __forceinline__ void block_amax_atomic(float mx, u32* scal, int s) {
#pragma unroll
  for (int off = 32; off; off >>= 1) mx = fmaxf(mx, __shfl_xor(mx, off));
  __shared__ float red[4];
  const int lane = threadIdx.x & 63, wave = threadIdx.x >> 6;
  if (lane == 0) red[wave] = mx;
  __syncthreads();
  if (threadIdx.x == 0) {
    float m = fmaxf(fmaxf(red[0], red[1]), fmaxf(red[2], red[3]));
    atomicMax(scal + (blockIdx.x & 15) * 16 + s, __float_as_uint(m));
  }
}

// two amaxes with one barrier
__device__ __forceinline__ void block_amax2(float a, float b, u32* scal, int sa, int sb) {
#pragma unroll
  for (int off = 32; off; off >>= 1) {
    a = fmaxf(a, __shfl_xor(a, off));
    b = fmaxf(b, __shfl_xor(b, off));
  }
  __shared__ float red2[2][4];
  const int lane = threadIdx.x & 63, wave = threadIdx.x >> 6;
  if (lane == 0) { red2[0][wave] = a; red2[1][wave] = b; }
  __syncthreads();
  if (threadIdx.x == 0) {
    float ma = fmaxf(fmaxf(red2[0][0], red2[0][1]), fmaxf(red2[0][2], red2[0][3]));
    float mb = fmaxf(fmaxf(red2[1][0], red2[1][1]), fmaxf(red2[1][2], red2[1][3]));
    u32* base = scal + (blockIdx.x & 15) * 16;
    atomicMax(base + sa, __float_as_uint(ma));
    atomicMax(base + sb, __float_as_uint(mb));
  }
}

// ---------------- GEMM core (m97 structure) ----------------
// C[m,n] = sum_k A[m,k]*B[n,k]; row-major, row stride K (bf16 bits).
// 128x128 tile, BK=32, 4 waves each 64x64 via 4x4 MFMA 16x16x32.
// LDS swizzle: chunk q of row r holds granule q^((r>>1)&3) -> 2-way (free).
template <int K>
__device__ __forceinline__ void gemm_core(const u16* __restrict__ Ablk,
                                          const u16* __restrict__ Bblk,
                                          f32x4 acc[4][4], u16* smem) {
  u16* As = smem;          // 128*32
  u16* Bs = smem + 4096;   // 128*32
  const int tid = threadIdx.x;
  const int lane = tid & 63, wave = tid >> 6;
  const int wm = wave >> 1, wn = wave & 1;
  const int quad = lane >> 4, mrow = lane & 15;

  const int c0 = tid, c1 = tid + 256;
  const int r0 = c0 >> 2, g0 = ((c0 & 3) ^ ((r0 >> 1) & 3)) * 8;
  const int r1 = c1 >> 2, g1 = ((c1 & 3) ^ ((r1 >> 1) & 3)) * 8;
  const u16* a0 = Ablk + (size_t)r0 * K + g0;
  const u16* a1 = Ablk + (size_t)r1 * K + g1;
  const u16* b0 = Bblk + (size_t)r0 * K + g0;
  const u16* b1 = Bblk + (size_t)r1 * K + g1;
  u16* lA0 = &As[c0 * 8];
  u16* lA1 = &As[c1 * 8];
  u16* lB0 = &Bs[c0 * 8];
  u16* lB1 = &Bs[c1 * 8];

  int aoff[4], boff[4];
  const int lq = (quad ^ ((mrow >> 1) & 3)) * 8;
#pragma unroll
  for (int t = 0; t < 4; ++t) {
    aoff[t] = (wm * 64 + t * 16 + mrow) * 32 + lq;
    boff[t] = (wn * 64 + t * 16 + mrow) * 32 + lq;
  }

  for (int k0 = 0; k0 < K; k0 += 32) {
    __syncthreads();
    load_lds16(a0 + k0, lA0);
    load_lds16(a1 + k0, lA1);
    load_lds16(b0 + k0, lB0);
    load_lds16(b1 + k0, lB1);
    __syncthreads();
    bf16x8 af[4], bfr[4];
#pragma unroll
    for (int t = 0; t < 4; ++t) {
      af[t] = *(const bf16x8*)&As[aoff[t]];
      bfr[t] = *(const bf16x8*)&Bs[boff[t]];
    }
#pragma unroll
    for (int i = 0; i < 4; ++i)
#pragma unroll
      for (int j = 0; j < 4; ++j)
        acc[i][j] = __builtin_amdgcn_mfma_f32_16x16x32_bf16(af[i], bfr[j], acc[i][j], 0, 0, 0);
  }
}

#define HSTRIDE 136  // 128 + 8 pad: quad rows land 2-way on banks (free)

// GEMM1: per block, same (m,n) region for gate then up.
// pass G: gate = xq @ wcat[3072+n..]^T -> store gate tile, amax(gate)->2,
//         h_a = g*sigq(g) -> hbuf (bf16), amax(h)->3.
// pass U: up = xq @ wcat[n..]^T -> store up tile, amax(up)->1,
//         o_a = h_a*up -> amax(o)->4.
__global__ void __launch_bounds__(256) kgemm1(const u16* __restrict__ xq,
                                              const u16* __restrict__ wcat,
                                              u16* __restrict__ up, u16* __restrict__ gh,
                                              u32* __restrict__ scal) {
  __shared__ __align__(16) u16 smem[8192];
  __shared__ __align__(16) u16 hbuf[128 * HSTRIDE];
  const int tileN = blockIdx.x * 128;
  const int tileM = blockIdx.y * 128;
  const int lane = threadIdx.x & 63, wave = threadIdx.x >> 6;
  const int wm = wave >> 1, wn = wave & 1;
  const int rb = (lane >> 4) * 4, cb = lane & 15;  // C/D: row=(l>>4)*4+reg, col=l&15
  const int erow = lane >> 2, echk = lane & 3;
  u16* wbase = smem + wave * 1152;  // 16 rows * 72
  const u16* rbase = wbase + erow * 72;
  const u16* Ablk = xq + (size_t)tileM * H_DIM;
  f32x4 acc[4][4];

  // ---------------- pass G (gate) ----------------
#pragma unroll
  for (int i = 0; i < 4; ++i)
#pragma unroll
    for (int j = 0; j < 4; ++j) acc[i][j] = (f32x4){0.f, 0.f, 0.f, 0.f};
  gemm_core<H_DIM>(Ablk, wcat + (size_t)(I_DIM + tileN) * H_DIM, acc, smem);
  {
    float mxg = 0.f, mxh = 0.f;
#pragma unroll
    for (int i = 0; i < 4; ++i) {
      __syncthreads();
#pragma unroll
      for (int j = 0; j < 4; ++j)
#pragma unroll
        for (int r = 0; r < 4; ++r) {
          float g = acc[i][j][r];
          mxg = fmaxf(mxg, fabsf(g));
          wbase[(rb + r) * 72 + j * 16 + cb] = f2bf(g);
          float ha = g * sigq(g);
          mxh = fmaxf(mxh, fabsf(ha));
          hbuf[(wm * 64 + i * 16 + rb + r) * HSTRIDE + wn * 64 + j * 16 + cb] = f2bf(ha);
        }
      __syncthreads();
      uint4 v0 = *(const uint4*)(rbase + echk * 8);
      uint4 v1 = *(const uint4*)(rbase + (echk + 4) * 8);
      size_t grow = (size_t)(tileM + wm * 64 + i * 16 + erow) * I_DIM + (tileN + wn * 64);
      *(uint4*)(gh + grow + echk * 8) = v0;
      *(uint4*)(gh + grow + (echk + 4) * 8) = v1;
    }
    block_amax2(mxg, mxh, scal, 2, 3);
  }

  // ---------------- pass U (up) ----------------
#pragma unroll
  for (int i = 0; i < 4; ++i)
#pragma unroll
    for (int j = 0; j < 4; ++j) acc[i][j] = (f32x4){0.f, 0.f, 0.f, 0.f};
  gemm_core<H_DIM>(Ablk, wcat + (size_t)tileN * H_DIM, acc, smem);
  {
    float mxu = 0.f, mxo = 0.f;
#pragma unroll
    for (int i = 0; i < 4; ++i) {
      __syncthreads();
#pragma unroll
      for (int j = 0; j < 4; ++j)
#pragma unroll
        for (int r = 0; r < 4; ++r) {
          float u = acc[i][j][r];
          mxu = fmaxf(mxu, fabsf(u));
          wbase[(rb + r) * 72 + j * 16 + cb] = f2bf(u);
          float ha = bf2f(hbuf[(wm * 64 + i * 16 + rb + r) * HSTRIDE + wn * 64 + j * 16 + cb]);
          mxo = fmaxf(mxo, fabsf(ha * u));
        }
      __syncthreads();
      uint4 v0 = *(const uint4*)(rbase + echk * 8);
      uint4 v1 = *(const uint4*)(rbase + (echk + 4) * 8);
      size_t grow = (size_t)(tileM + wm * 64 + i * 16 + erow) * I_DIM + (tileN + wn * 64);
      *(uint4*)(up + grow + echk * 8) = v0;
      *(uint4*)(up + grow + (echk + 4) * 8) = v1;
    }
    block_amax2(mxu, mxo, scal, 1, 4);
  }
}

// GEMM2: oq[8192,3072] x wdq[1024,3072]^T -> out fp32 [8192,1024]
__global__ void __launch_bounds__(256) kgemm2(const u16* __restrict__ oq,
                                              const u16* __restrict__ wdq,
                                              float* __restrict__ out) {
  __shared__ __align__(16) u16 smem[8192];
  const int tileN = blockIdx.x * 128;
  const int tileM = blockIdx.y * 128;
  f32x4 acc[4][4];
#pragma unroll
  for (int i = 0; i < 4; ++i)
#pragma unroll
    for (int j = 0; j < 4; ++j) acc[i][j] = (f32x4){0.f, 0.f, 0.f, 0.f};
  gemm_core<I_DIM>(oq + (size_t)tileM * I_DIM, wdq + (size_t)tileN * I_DIM, acc, smem);

  const int lane = threadIdx.x & 63, wave = threadIdx.x >> 6;
  const int wm = wave >> 1, wn = wave & 1;
  const int rb = (lane >> 4) * 4, cb = lane & 15;
#pragma unroll
  for (int i = 0; i < 4; ++i) {
#pragma unroll
    for (int j = 0; j < 4; ++j) {
      size_t base = (size_t)(tileM + wm * 64 + i * 16 + rb) * H_DIM +
                    (size_t)(tileN + wn * 64 + j * 16 + cb);
#pragma unroll
      for (int r = 0; r < 4; ++r) out[base + (size_t)r * H_DIM] = acc[i][j][r];
    }
  }
}

// ---------------- prep: absmax(x) (blocks 0..1023) + LPBQ dequant (rest) ----
__global__ void __launch_bounds__(256) kprep(const float* __restrict__ x,
                                             const float* __restrict__ wu,
                                             const float* __restrict__ wg,
                                             const float* __restrict__ wdn,
                                             u16* __restrict__ wcat, u16* __restrict__ wdq,
                                             u32* __restrict__ scal) {
  if (blockIdx.x < 1024) {
    const float4* x4 = (const float4*)x;
    const int n4 = (M_ROWS * H_DIM) / 4;
    float mx = 0.f;
    for (int i = blockIdx.x * 256 + threadIdx.x; i < n4; i += 1024 * 256) {
      float4 v = x4[i];
      mx = fmaxf(fmaxf(fabsf(v.x), fabsf(v.y)), fmaxf(fmaxf(fabsf(v.z), fabsf(v.w)), mx));
    }
    block_amax_atomic(mx, scal, 0);
    return;
  }
  const int gid = (blockIdx.x - 1024) * 256 + threadIdx.x;
  const int unit = gid >> 3, l8 = gid & 7;
  const float* src;
  u16* dst;
  int u;
  if (unit < 98304)       { src = wu;  dst = wcat;            u = unit; }
  else if (unit < 196608) { src = wg;  dst = wcat + 3145728;  u = unit - 98304; }
  else                    { src = wdn; dst = wdq;             u = unit - 196608; }
  const size_t off = (size_t)u * 32 + (size_t)l8 * 4;
  float4 v = *(const float4*)(src + off);
  float m = fmaxf(fmaxf(fabsf(v.x), fabsf(v.y)), fmaxf(fabsf(v.z), fabsf(v.w)));
  m = fmaxf(m, __shfl_xor(m, 1));
  m = fmaxf(m, __shfl_xor(m, 2));
  m = fmaxf(m, __shfl_xor(m, 4));
  const float s = fmaxf(m / 7.0f, 1e-12f);
  const float inv = 1.0f / s;
  float vv[4] = {v.x, v.y, v.z, v.w};
  u16 o[4];
#pragma unroll
  for (int e = 0; e < 4; ++e) {
    float q = rintf(vv[e] * inv);
    q = fminf(fmaxf(q, -8.f), 7.f);
    o[e] = f2bf(q * s);
  }
  *(ushort4*)(dst + off) = make_ushort4(o[0], o[1], o[2], o[3]);
}

__global__ void __launch_bounds__(256) kqdqx(const float4* __restrict__ x,
                                             ushort4* __restrict__ xq,
                                             const u32* __restrict__ scal) {
  const float s = scale_read(scal, 0);
  const float inv = 1.0f / s;
  const int i = blockIdx.x * 256 + threadIdx.x;
  float4 v = x[i];
  ushort4 o;
  o.x = f2bf(qdq16i(v.x, inv, s));
  o.y = f2bf(qdq16i(v.y, inv, s));
  o.z = f2bf(qdq16i(v.z, inv, s));
  o.w = f2bf(qdq16i(v.w, inv, s));
  xq[i] = o;
}

#define GH4 ((M_ROWS * I_DIM) / 8)
#define EW_BLOCKS 2048

// exact chain: g_q=qdq(g,sg); h=g_q*sigq(g_q); h_q=qdq(h,sh);
// o=h_q*qdq(u,su); oq=bf16(qdq(o,so)) -> gh (in place)
__global__ void __launch_bounds__(256) kmulo(uint4* __restrict__ gh, const uint4* __restrict__ up,
                                             u32* __restrict__ scal) {
  const float sg = scale_read(scal, 2), ig = 1.0f / sg;
  const float sh = scale_read(scal, 3), ih = 1.0f / sh;
  const float su = scale_read(scal, 1), iu = 1.0f / su;
  const float so = scale_read(scal, 4), io = 1.0f / so;
  for (int i = blockIdx.x * 256 + threadIdx.x; i < GH4; i += EW_BLOCKS * 256) {
    union { uint4 v; u16 us[8]; } a, b;
    a.v = gh[i];
    b.v = up[i];
#pragma unroll
    for (int e = 0; e < 8; ++e) {
      float g = qdq16i(bf2f(a.us[e]), ig, sg);
      float h = g * sigq(g);
      float o = qdq16i(h, ih, sh) * qdq16i(bf2f(b.us[e]), iu, su);
      a.us[e] = f2bf(qdq16i(o, io, so));
    }
    gh[i] = a.v;
  }
}

extern "C" void kernel_launch(void* const* d_in, const int* in_sizes, int n_in,
                              void* d_out, int out_size, void* d_ws, size_t ws_size,
                              hipStream_t stream) {
  (void)in_sizes; (void)n_in; (void)out_size; (void)ws_size;
  const float* x   = (const float*)d_in[0];
  const float* wg  = (const float*)d_in[1];
  const float* wu  = (const float*)d_in[2];
  const float* wdn = (const float*)d_in[3];
  float* out = (float*)d_out;
  char* ws = (char*)d_ws;

  u32* scal = (u32*)ws;
  u16* xq   = (u16*)(ws + 1024);                    // 8192*1024
  u16* wcat = xq + (size_t)M_ROWS * H_DIM;          // 6144*1024 (up rows, then gate rows)
  u16* wdq  = wcat + (size_t)2 * I_DIM * H_DIM;     // 1024*3072
  u16* up   = wdq + (size_t)H_DIM * I_DIM;          // 8192*3072
  u16* gh   = up + (size_t)M_ROWS * I_DIM;          // 8192*3072 (gate -> oq)

  hipMemsetAsync(scal, 0, 1024, stream);
  kprep<<<1024 + 9216, 256, 0, stream>>>(x, wu, wg, wdn, wcat, wdq, scal);
  kqdqx<<<(M_ROWS * H_DIM) / 4 / 256, 256, 0, stream>>>((const float4*)x, (ushort4*)xq, scal);
  kgemm1<<<dim3(24, 64), 256, 0, stream>>>(xq, wcat, up, gh, scal);
  kmulo<<<EW_BLOCKS, 256, 0, stream>>>((uint4*)gh, (const uint4*)up, scal);
  kgemm2<<<dim3(8, 64), 256, 0, stream>>>(gh, wdq, out);
}